// Round 5
// baseline (468.639 us; speedup 1.0000x reference)
//
#include <hip/hip_runtime.h>

namespace {
constexpr int NP      = 64;       // pulses
constexpr int BATCH_N = 16384;    // batch
constexpr int NS      = 21;       // EPG states
constexpr int BPB     = 16;       // batch elems per block: 16*21*4 = 1344 B = 21 FULL
                                  // 64B lines per plane-pulse (lcm(84,64)=1344)
constexpr int CHAN    = BATCH_N * NS;                 // 344064 floats/plane
constexpr unsigned CHANB = (unsigned)CHAN * 4u;       // 1376256 B
constexpr unsigned STEPB = 5u * CHANB;                // 6881280 B per pulse
constexpr int LDSF    = BPB * NS * 5;                 // 1680 floats / buffer
constexpr int NSLOT   = LDSF / 4;                     // 420 float4 per flush
constexpr int TPB     = 384;                          // 6 waves
typedef float vf4 __attribute__((ext_vector_type(4)));  // native vec for builtins
}

// One lane per (batch, state); 3 batch elems per wave (waves 0-4), wave 5
// carries batch elem 15 only (idx 16,17 masked). Gradient shift = shfl by 1;
// s==0 / s==20 zero-masks absorb the cross-batch shuffle leak.
//
// vs round 4 (single isolated change): REGULAR vf4 stores instead of
// __builtin_nontemporal_store. Every store is still a full, aligned 64B-line
// span (BPB=16 geometry), so no write-allocate RMW is possible; regular
// cached stores get L2 write-combining/aggregation that the nt flag bypasses.
// A/B discriminator: fill fixture reaches 6.3 TB/s with regular stores while
// the NT stream appears capped near 2.5 TB/s.
__global__ __launch_bounds__(TPB) void epg_kernel(
    const float* __restrict__ flip, const float* __restrict__ ph,
    const float* __restrict__ T1,   const float* __restrict__ T2,
    const float* __restrict__ B0,   const float* __restrict__ B1,
    const int*   __restrict__ TRp,  float* __restrict__ out)
{
  __shared__ __align__(16) float lds[2][LDSF];   // 13440 B
  __shared__ __align__(16) float tbl[NP][8];     // pulse-uniform trig table

  const int tid  = threadIdx.x;

  // ---- pulse-uniform table: a = flip[p], eib = er + i*ei, eib^2 = w2r + i*w2i
  if (tid < NP) {
    const float a = flip[tid];
    const float b = ph[tid];
    float ei, er; __sincosf(b, &ei, &er);
    tbl[tid][0] = a;
    tbl[tid][1] = er;
    tbl[tid][2] = ei;
    tbl[tid][3] = er * er - ei * ei;
    tbl[tid][4] = 2.0f * er * ei;
  }

  const int lane = tid & 63;
  const int wv   = tid >> 6;             // 0..5
  const int sub  = lane / 21;            // 0..2 real, 3 = idle lane 63
  const int s    = lane - sub * 21;      // state index 0..20
  const int idx  = wv * 3 + sub;         // 0..17
  const bool active = (sub < 3) && (idx < BPB);
  const int  bg  = blockIdx.x * BPB + (active ? idx : 0);  // always in range
  const int  inner = idx * NS + s;       // [0,336) when active

  // ---- flush-slot precompute (fixed per thread); per-plane float4 count = 84
  const unsigned base0 = (unsigned)blockIdx.x * (BPB * NS * 4u); // 1344*blk, 64B-aligned
  int      loff[2]; unsigned goff[2]; bool fdo[2];
  #pragma unroll
  for (int k = 0; k < 2; ++k) {
    const int i = tid + k * TPB;
    const int c = i / 84;                // plane 0..4
    const int j = i - c * 84;            // float4 index within plane span
    fdo[k]  = (i < NSLOT);               // 16384 % 16 == 0: no ragged block
    loff[k] = c * (BPB * NS) + 4 * j;
    goff[k] = base0 + (unsigned)c * CHANB + (unsigned)j * 16u;
  }

  // ---- per-lane physics setup ----
  const float TR = (float)TRp[0];
  const float E1 = __expf(-TR / T1[bg]);
  const float E2 = __expf(-TR / T2[bg]);
  const float b1 = B1[bg];
  const float rec = (s == 0) ? (1.0f - E1) : 0.0f;   // Z recovery, k==0 only
  const float phi = 6.283185307179586f * 0.001f * TR * B0[bg];
  float bi, br; __sincosf(phi, &bi, &br);            // eb0p = br + i*bi

  float fpr = 0.f, fpi = 0.f, fmr = 0.f, fmi = 0.f;
  float z = (s == 0) ? 1.0f : 0.0f;

  char* const outb = (char*)out;
  unsigned pbase = 0;
  int buf = 0;

  __syncthreads();   // tbl ready (full sync once; vmcnt here is only reads)

  #pragma unroll 2
  for (int p = 0; p < NP; ++p) {
    const vf4 tq = *(const vf4*)&tbl[p][0];          // broadcast ds_read_b128
    const float a   = tq.x;
    const float er  = tq.y, ei  = tq.z;              // eib
    const float w2r = tq.w;
    const float w2i = tbl[p][4];                     // eib^2 imag

    float sa, ca; __sincosf(0.5f * a * b1, &sa, &ca);
    const float c2 = ca * ca, s2 = sa * sa, cs = ca * sa;

    // relaxation
    fpr *= E2; fpi *= E2; fmr *= E2; fmi *= E2;
    z = E1 * z + rec;

    // B0 precession: Fp *= eb0p, Fm *= conj(eb0p)
    {
      float t = fpr * br - fpi * bi;
      fpi = fpr * bi + fpi * br; fpr = t;
      float u = fmr * br + fmi * bi;
      fmi = fmi * br - fmr * bi; fmr = u;
    }

    // RF rotation
    const float zcs = cs * z;
    const float fpnr =  c2 * fpr + s2 * (fmr * w2r + fmi * w2i) - zcs * ei;
    const float fpni =  c2 * fpi + s2 * (fmr * w2i - fmi * w2r) + zcs * er;
    const float fmnr =  c2 * fmr + s2 * (fpr * w2r - fpi * w2i) - zcs * ei;
    const float fmni =  c2 * fmi - s2 * (fpr * w2i + fpi * w2r) - zcs * er;
    const float zn   =  cs * ((fpi - fmi) * er - (fpr + fmr) * ei)
                        + (c2 - s2) * z;

    // gradient shift: Fp up one state, Fm down one state
    const float ufpr = __shfl_up(fpnr, 1);
    const float ufpi = __shfl_up(fpni, 1);
    const float dfmr = __shfl_down(fmnr, 1);
    const float dfmi = __shfl_down(fmni, 1);
    fpr = (s == 0)  ? 0.f : ufpr;
    fpi = (s == 0)  ? 0.f : ufpi;
    fmr = (s == 20) ? 0.f : dfmr;
    fmi = (s == 20) ? 0.f : dfmi;
    z = zn;

    // stage this pulse's output in LDS: layout [c][b][s]
    if (active) {
      float* lb = lds[buf];
      lb[inner]                = fpr;   // Fp_s.real
      lb[BPB * NS + inner]     = fpi;   // Fp_s.imag
      lb[2 * BPB * NS + inner] = fmr;   // Fm_s.real
      lb[3 * BPB * NS + inner] = fmi;   // Fm_s.imag
      lb[4 * BPB * NS + inner] = zn;    // Z_n
    }

    // LDS-only barrier: ds_writes visible, global stores stay in flight
    asm volatile("s_waitcnt lgkmcnt(0)" ::: "memory");
    __builtin_amdgcn_s_barrier();
    __builtin_amdgcn_sched_barrier(0);   // rule #18: don't hoist ds_reads above

    // flush: regular vf4 stores, every one a full aligned-line span
    {
      const float* lb = lds[buf];
      #pragma unroll
      for (int k = 0; k < 2; ++k) {
        if (fdo[k]) {
          const vf4 v = *(const vf4*)&lb[loff[k]];
          *(vf4*)(outb + pbase + goff[k]) = v;
        }
      }
    }
    buf ^= 1;
    pbase += STEPB;
  }
}

extern "C" void kernel_launch(void* const* d_in, const int* in_sizes, int n_in,
                              void* d_out, int out_size, void* d_ws, size_t ws_size,
                              hipStream_t stream) {
  const float* flip = (const float*)d_in[0];
  const float* ph   = (const float*)d_in[1];
  const float* T1   = (const float*)d_in[2];
  const float* T2   = (const float*)d_in[3];
  const float* B0   = (const float*)d_in[4];
  const float* B1   = (const float*)d_in[5];
  const int*   TR   = (const int*)d_in[6];
  // d_in[7] = TE, unused by the reference output
  float* out = (float*)d_out;

  const int blocks = BATCH_N / BPB;   // 1024
  epg_kernel<<<blocks, TPB, 0, stream>>>(flip, ph, T1, T2, B0, B1, TR, out);
}

// Round 6
// 452.475 us; speedup vs baseline: 1.0357x; 1.0357x over previous
//
#include <hip/hip_runtime.h>

namespace {
constexpr int NP      = 64;       // pulses
constexpr int BATCH_N = 16384;    // batch
constexpr int NS      = 21;       // EPG states
constexpr int BPB     = 16;       // batch elems per block: 16*21*4 = 1344 B = 21 FULL
                                  // 64B lines per plane-pulse (lcm(84,64)=1344)
constexpr int CHAN    = BATCH_N * NS;                 // 344064 floats/plane
constexpr unsigned CHANB = (unsigned)CHAN * 4u;       // 1376256 B
constexpr unsigned STEPB = 5u * CHANB;                // 6881280 B per pulse
constexpr int LDSF    = BPB * NS * 5;                 // 1680 floats / pulse-buffer
constexpr int NSLOT   = LDSF / 4;                     // 420 float4 per pulse flush
constexpr int TPB     = 384;                          // 6 waves
typedef float vf4 __attribute__((ext_vector_type(4)));  // native vec for builtins
}

// One lane per (batch, state); 3 batch elems per wave (waves 0-4), wave 5
// carries batch elem 15 only. Gradient shift = shfl by 1; s==0 / s==20
// zero-masks absorb the cross-batch shuffle leak.
//
// vs round 4 (single isolated change): TWO pulses staged per barrier.
// Ledger: 64-barrier variants all sit at epg~170-175us vs 70us write floor;
// vmcnt-drain removal tied (r4) -> stores weren't gated by drain but by the
// per-pulse barrier CADENCE (2KB/wave/barrier-period bursts). Halving the
// barrier count and doubling the flush burst tests cadence-boundedness.
// 32 barriers; flush = 2 pulses x 420 NT line-aligned float4s; LDS dbuf
// 2 groups x 2 pulses (26.9KB, still 5 blocks/CU).
__global__ __launch_bounds__(TPB) void epg_kernel(
    const float* __restrict__ flip, const float* __restrict__ ph,
    const float* __restrict__ T1,   const float* __restrict__ T2,
    const float* __restrict__ B0,   const float* __restrict__ B1,
    const int*   __restrict__ TRp,  float* __restrict__ out)
{
  __shared__ __align__(16) float lds[2][2][LDSF];   // 26880 B
  __shared__ __align__(16) float tbl[NP][8];        // pulse-uniform trig table

  const int tid  = threadIdx.x;

  // ---- pulse-uniform table: a = flip[p], eib = er + i*ei, eib^2 = w2r + i*w2i
  if (tid < NP) {
    const float a = flip[tid];
    const float b = ph[tid];
    float ei, er; __sincosf(b, &ei, &er);
    tbl[tid][0] = a;
    tbl[tid][1] = er;
    tbl[tid][2] = ei;
    tbl[tid][3] = er * er - ei * ei;
    tbl[tid][4] = 2.0f * er * ei;
  }

  const int lane = tid & 63;
  const int wv   = tid >> 6;             // 0..5
  const int sub  = lane / 21;            // 0..2 real, 3 = idle lane 63
  const int s    = lane - sub * 21;      // state index 0..20
  const int idx  = wv * 3 + sub;         // 0..17
  const bool active = (sub < 3) && (idx < BPB);
  const int  bg  = blockIdx.x * BPB + (active ? idx : 0);  // always in range
  const int  inner = idx * NS + s;       // [0,336) when active

  // ---- flush-slot precompute (fixed per thread); per-plane float4 count = 84
  const unsigned base0 = (unsigned)blockIdx.x * (BPB * NS * 4u); // 1344*blk, 64B-aligned
  int      loff[2]; unsigned goff[2]; bool fdo[2];
  #pragma unroll
  for (int k = 0; k < 2; ++k) {
    const int i = tid + k * TPB;
    const int c = i / 84;                // plane 0..4
    const int j = i - c * 84;            // float4 index within plane span
    fdo[k]  = (i < NSLOT);               // 16384 % 16 == 0: no ragged block
    loff[k] = c * (BPB * NS) + 4 * j;
    goff[k] = base0 + (unsigned)c * CHANB + (unsigned)j * 16u;
  }

  // ---- per-lane physics setup ----
  const float TR = (float)TRp[0];
  const float E1 = __expf(-TR / T1[bg]);
  const float E2 = __expf(-TR / T2[bg]);
  const float b1 = B1[bg];
  const float rec = (s == 0) ? (1.0f - E1) : 0.0f;   // Z recovery, k==0 only
  const float phi = 6.283185307179586f * 0.001f * TR * B0[bg];
  float bi, br; __sincosf(phi, &bi, &br);            // eb0p = br + i*bi

  float fpr = 0.f, fpi = 0.f, fmr = 0.f, fmi = 0.f;
  float z = (s == 0) ? 1.0f : 0.0f;

  char* const outb = (char*)out;
  unsigned pbase = 0;
  int buf = 0;

  __syncthreads();   // tbl ready

  for (int g = 0; g < NP / 2; ++g) {
    // ---- compute + stage two pulses, no intervening barrier ----
    #pragma unroll
    for (int q = 0; q < 2; ++q) {
      const int p = 2 * g + q;
      const vf4 tq = *(const vf4*)&tbl[p][0];          // broadcast ds_read_b128
      const float a   = tq.x;
      const float er  = tq.y, ei  = tq.z;              // eib
      const float w2r = tq.w;
      const float w2i = tbl[p][4];                     // eib^2 imag

      float sa, ca; __sincosf(0.5f * a * b1, &sa, &ca);
      const float c2 = ca * ca, s2 = sa * sa, cs = ca * sa;

      // relaxation
      fpr *= E2; fpi *= E2; fmr *= E2; fmi *= E2;
      z = E1 * z + rec;

      // B0 precession: Fp *= eb0p, Fm *= conj(eb0p)
      {
        float t = fpr * br - fpi * bi;
        fpi = fpr * bi + fpi * br; fpr = t;
        float u = fmr * br + fmi * bi;
        fmi = fmi * br - fmr * bi; fmr = u;
      }

      // RF rotation
      const float zcs = cs * z;
      const float fpnr =  c2 * fpr + s2 * (fmr * w2r + fmi * w2i) - zcs * ei;
      const float fpni =  c2 * fpi + s2 * (fmr * w2i - fmi * w2r) + zcs * er;
      const float fmnr =  c2 * fmr + s2 * (fpr * w2r - fpi * w2i) - zcs * ei;
      const float fmni =  c2 * fmi - s2 * (fpr * w2i + fpi * w2r) - zcs * er;
      const float zn   =  cs * ((fpi - fmi) * er - (fpr + fmr) * ei)
                          + (c2 - s2) * z;

      // gradient shift: Fp up one state, Fm down one state
      const float ufpr = __shfl_up(fpnr, 1);
      const float ufpi = __shfl_up(fpni, 1);
      const float dfmr = __shfl_down(fmnr, 1);
      const float dfmi = __shfl_down(fmni, 1);
      fpr = (s == 0)  ? 0.f : ufpr;
      fpi = (s == 0)  ? 0.f : ufpi;
      fmr = (s == 20) ? 0.f : dfmr;
      fmi = (s == 20) ? 0.f : dfmi;
      z = zn;

      // stage this pulse's output in LDS: layout [c][b][s]
      if (active) {
        float* lb = &lds[buf][q][0];
        lb[inner]                = fpr;   // Fp_s.real
        lb[BPB * NS + inner]     = fpi;   // Fp_s.imag
        lb[2 * BPB * NS + inner] = fmr;   // Fm_s.real
        lb[3 * BPB * NS + inner] = fmi;   // Fm_s.imag
        lb[4 * BPB * NS + inner] = zn;    // Z_n
      }
    }

    // LDS-only barrier: ds_writes visible, NT stores stay in flight
    asm volatile("s_waitcnt lgkmcnt(0)" ::: "memory");
    __builtin_amdgcn_s_barrier();
    __builtin_amdgcn_sched_barrier(0);   // rule #18: don't hoist ds_reads above

    // flush BOTH pulses: NT vf4 stores, every one a full aligned-line span
    #pragma unroll
    for (int q = 0; q < 2; ++q) {
      const float* lb = &lds[buf][q][0];
      const unsigned pb = pbase + (unsigned)q * STEPB;
      #pragma unroll
      for (int k = 0; k < 2; ++k) {
        if (fdo[k]) {
          const vf4 v = *(const vf4*)&lb[loff[k]];
          __builtin_nontemporal_store(v, (vf4*)(outb + pb + goff[k]));
        }
      }
    }
    buf ^= 1;
    pbase += 2u * STEPB;
  }
}

extern "C" void kernel_launch(void* const* d_in, const int* in_sizes, int n_in,
                              void* d_out, int out_size, void* d_ws, size_t ws_size,
                              hipStream_t stream) {
  const float* flip = (const float*)d_in[0];
  const float* ph   = (const float*)d_in[1];
  const float* T1   = (const float*)d_in[2];
  const float* T2   = (const float*)d_in[3];
  const float* B0   = (const float*)d_in[4];
  const float* B1   = (const float*)d_in[5];
  const int*   TR   = (const int*)d_in[6];
  // d_in[7] = TE, unused by the reference output
  float* out = (float*)d_out;

  const int blocks = BATCH_N / BPB;   // 1024
  epg_kernel<<<blocks, TPB, 0, stream>>>(flip, ph, T1, T2, B0, B1, TR, out);
}